// Round 1
// baseline (31665.964 us; speedup 1.0000x reference)
//
#include <hip/hip_runtime.h>

#define Hh 1024
#define Vv 512
#define Bb 128
#define Tt 512
#define TV (Tt * Vv) /* 262144 */

typedef unsigned short u16;
typedef unsigned int u32;
typedef __attribute__((ext_vector_type(8))) short bf16x8;
typedef __attribute__((ext_vector_type(4))) float floatx4;

// ---------- ws layout (bytes) ----------
#define WS_WGA 0                    // 4*64*48*512 u16 = 12,582,912 B
#define WS_WYA 12582912             // 32*32*512 u16   =  1,048,576 B
#define WS_AF0 13631488             // 131072 u16      =    262,144 B
#define WS_AF1 13893632             // 131072 u16      =    262,144 B
#define WS_CTRL 14155776            // ctrl[0]=count ctrl[1]=gen ; +64: loss acc

__device__ __forceinline__ u16 f2bf(float f) {
    union { float f; u32 u; } c; c.f = f;
    u32 u = c.u + 0x7fffu + ((c.u >> 16) & 1u);   // RNE
    return (u16)(u >> 16);
}
__device__ __forceinline__ float sigm(float x) { return 1.0f / (1.0f + __expf(-x)); }
__device__ __forceinline__ float tanh_f(float x) {
    float e = __expf(-2.0f * fabsf(x));
    float t = (1.0f - e) / (1.0f + e);
    return x >= 0.0f ? t : -t;
}

// ---------- pack W{f,u,cc,o} (1024x1536 f32) -> fragment-linear bf16 ----------
// out idx = ((g*64 + i)*48 + kt)*512 + l*8 + j  <->  W[i*16 + (l&15)][kt*32 + ((l>>4)&3)*8 + j]
__global__ __launch_bounds__(256) void pack_gates(const float* __restrict__ Wf, const float* __restrict__ Wu,
                                                  const float* __restrict__ Wc, const float* __restrict__ Wo,
                                                  u16* __restrict__ WgA) {
    int tid = blockIdx.x * 256 + threadIdx.x;  // 786432 total
    int l = tid & 63;
    int q = tid >> 6;
    int kt = q % 48; q /= 48;
    int i = q & 63;  int g = q >> 6;
    const float* W = (g == 0) ? Wf : (g == 1) ? Wu : (g == 2) ? Wc : Wo;
    int row = i * 16 + (l & 15);
    int k = kt * 32 + ((l >> 4) & 3) * 8;
    const float* src = W + (size_t)row * 1536 + k;
    float4 a = *(const float4*)src;
    float4 b = *(const float4*)(src + 4);
    bf16x8 v;
    v[0] = (short)f2bf(a.x); v[1] = (short)f2bf(a.y); v[2] = (short)f2bf(a.z); v[3] = (short)f2bf(a.w);
    v[4] = (short)f2bf(b.x); v[5] = (short)f2bf(b.y); v[6] = (short)f2bf(b.z); v[7] = (short)f2bf(b.w);
    *(bf16x8*)(WgA + (size_t)tid * 8) = v;
}

// ---------- pack Wy (512x1024 f32) -> fragment-linear bf16 ----------
__global__ __launch_bounds__(256) void pack_wy(const float* __restrict__ Wy, u16* __restrict__ WyA) {
    int tid = blockIdx.x * 256 + threadIdx.x;  // 65536 total
    int l = tid & 63;
    int q = tid >> 6;
    int kt = q & 31; int i = q >> 5;
    int row = i * 16 + (l & 15);
    int k = kt * 32 + ((l >> 4) & 3) * 8;
    const float* src = Wy + (size_t)row * 1024 + k;
    float4 a = *(const float4*)src;
    float4 b = *(const float4*)(src + 4);
    bf16x8 v;
    v[0] = (short)f2bf(a.x); v[1] = (short)f2bf(a.y); v[2] = (short)f2bf(a.z); v[3] = (short)f2bf(a.w);
    v[4] = (short)f2bf(b.x); v[5] = (short)f2bf(b.y); v[6] = (short)f2bf(b.z); v[7] = (short)f2bf(b.w);
    *(bf16x8*)(WyA + (size_t)tid * 8) = v;
}

// ---------- pack a_prev (H,B f32) -> fragment-linear bf16 a-buffer ----------
// a-frag layout: idx = (kt*8 + ch)*512 + lane*8 + j ; h = kt*32 + ((lane>>4)&3)*8 + j ; b = ch*16 + (lane&15)
__global__ __launch_bounds__(256) void pack_a(const float* __restrict__ ap, u16* __restrict__ aF0) {
    int o = blockIdx.x * 256 + threadIdx.x;  // 131072 total
    int j = o & 7, li = (o >> 3) & 63, seg = o >> 9;
    int kt = seg >> 3, ch = seg & 7;
    int h = kt * 32 + ((li >> 4) & 3) * 8 + j;
    int b = ch * 16 + (li & 15);
    aF0[o] = f2bf(ap[(size_t)h * Bb + b]);
}

// ---------- main persistent LSTM kernel (cooperative, 256 blocks x 512 thr) ----------
__global__ __launch_bounds__(512, 2) void lstm_main(
    const float* __restrict__ X, const float* __restrict__ bfp, const float* __restrict__ bup,
    const float* __restrict__ bcp, const float* __restrict__ bop, const float* __restrict__ byp,
    const float* __restrict__ c_prev, const u16* __restrict__ WgA, const u16* __restrict__ WyA,
    u16* __restrict__ aF0, u16* __restrict__ aF1, float* __restrict__ out, u32* __restrict__ ctrl)
{
    __shared__ __align__(16) u16 xs[16384];    // 32 KB: x_t staged frag-linear (32 segs x 512 u16)
    __shared__ __align__(16) float pred[4096]; // 16 KB: gate partials / y reduction

    const int tid = threadIdx.x;
    const int bid = blockIdx.x;
    const int l = tid & 63;
    const int w = tid >> 6;        // wave 0..7
    const int g = w & 3;           // gate (f,u,cc,o)
    const int kh = w >> 2;         // K half (24 kt each)
    const int hc = bid & 63;       // h-chunk (16 rows)  -> bid%8 = hc%8 keeps weights XCD-local
    const int cc2 = bid >> 6;      // col chunk (32 cols)
    const int c0 = cc2 * 32;
    const int fm = l & 15;
    const int fq = l >> 4;         // 0..3
    const int fk = fq * 8;

    // elementwise coords: thread -> (em,en) in 16x32 tile
    const int em = tid >> 5;       // 0..15
    const int en = tid & 31;       // 0..31
    const int hrow = hc * 16 + em;
    const int bcol = c0 + en;
    float c_val = c_prev[(size_t)hrow * Bb + bcol];
    const float bfv = bfp[hrow], buv = bup[hrow], bcv = bcp[hrow], bov = bop[hrow];
    // a_new write slot in frag layout
    const int a_kt = hrow >> 5;
    const int a_q = (hrow >> 3) & 3;
    const int a_j = hrow & 7;
    const int a_ch = bcol >> 4;
    const int a_lane = (a_q << 4) | (bcol & 15);
    const int aWidx = ((a_kt << 3) + a_ch) * 512 + a_lane * 8 + a_j;
    // y-GEMM tile: 512x128 out = 32 v-tiles x 8 b-tiles
    const int yi = bid & 31;
    const int yc = bid >> 5;
    const int ymrow = yi * 16;

    const u16* Ab = WgA + (size_t)(g * 64 + hc) * 48 * 512;

    for (int t = 0; t < Tt; ++t) {
        const u16* aCur = (t & 1) ? aF1 : aF0;
        u16* aNxt = (t & 1) ? aF0 : aF1;

        // ---- stage x_t (V x 32 cols) into LDS, frag-linear bf16 ----
        {
            const float* Xt = X + (size_t)t * Vv;
#pragma unroll
            for (int it = 0; it < 4; ++it) {
                int s = w + 8 * it;            // 0..31
                int kt2 = s >> 1, half = s & 1;
                int b = c0 + half * 16 + fm;
                const float* p = Xt + (size_t)b * TV + kt2 * 32 + fk;
                float4 x0 = *(const float4*)p;
                float4 x1 = *(const float4*)(p + 4);
                bf16x8 v;
                v[0] = (short)f2bf(x0.x); v[1] = (short)f2bf(x0.y); v[2] = (short)f2bf(x0.z); v[3] = (short)f2bf(x0.w);
                v[4] = (short)f2bf(x1.x); v[5] = (short)f2bf(x1.y); v[6] = (short)f2bf(x1.z); v[7] = (short)f2bf(x1.w);
                *(bf16x8*)(xs + s * 512 + l * 8) = v;
            }
        }
        __syncthreads();

        // ---- gate GEMM: wave (g, kh): 16x32 partial over 24 k-tiles ----
        floatx4 acc0 = {0.f, 0.f, 0.f, 0.f}, acc1 = {0.f, 0.f, 0.f, 0.f};
        {
            const int kt0 = kh * 24;
#pragma unroll
            for (int kk = 0; kk < 24; ++kk) {
                int kt = kt0 + kk;
                bf16x8 a = *(const bf16x8*)(Ab + (size_t)kt * 512 + l * 8);
                bf16x8 b0, b1;
                if (kt < 32) {  // recurrent part from global a-buffer (frag-linear, coalesced)
                    int seg = kt * 8 + cc2 * 2;
                    b0 = *(const bf16x8*)(aCur + (size_t)seg * 512 + l * 8);
                    b1 = *(const bf16x8*)(aCur + (size_t)(seg + 1) * 512 + l * 8);
                } else {        // x part from LDS
                    int s = (kt - 32) * 2;
                    b0 = *(const bf16x8*)(xs + s * 512 + l * 8);
                    b1 = *(const bf16x8*)(xs + (s + 1) * 512 + l * 8);
                }
                acc0 = __builtin_amdgcn_mfma_f32_16x16x32_bf16(a, b0, acc0, 0, 0, 0);
                acc1 = __builtin_amdgcn_mfma_f32_16x16x32_bf16(a, b1, acc1, 0, 0, 0);
            }
        }
        {
            float* pw = pred + w * 512;
#pragma unroll
            for (int r = 0; r < 4; ++r) {
                int m = fq * 4 + r;            // C/D row = (lane>>4)*4 + reg
                pw[m * 32 + fm] = acc0[r];
                pw[m * 32 + 16 + fm] = acc1[r];
            }
        }
        __syncthreads();

        // ---- elementwise gates, c/a update ----
        {
            int o = em * 32 + en;
            float gf = pred[o]            + pred[4 * 512 + o] + bfv;
            float gu = pred[512 + o]      + pred[5 * 512 + o] + buv;
            float gc = pred[2 * 512 + o]  + pred[6 * 512 + o] + bcv;
            float go = pred[3 * 512 + o]  + pred[7 * 512 + o] + bov;
            float f = sigm(gf), u = sigm(gu), cc = tanh_f(gc), oo = sigm(go);
            c_val = f * c_val + u * cc;
            float a_new = oo * tanh_f(c_val);
            aNxt[aWidx] = f2bf(a_new);
        }

        // ---- grid barrier (1 per step) ----
        __syncthreads();   // drains all waves' global stores before fence
        if (tid == 0) {
            __threadfence();
            u32 g0 = __hip_atomic_load(ctrl + 1, __ATOMIC_RELAXED, __HIP_MEMORY_SCOPE_AGENT);
            u32 arr = __hip_atomic_fetch_add(ctrl, 1u, __ATOMIC_ACQ_REL, __HIP_MEMORY_SCOPE_AGENT);
            if (arr == gridDim.x - 1) {
                __hip_atomic_store(ctrl, 0u, __ATOMIC_RELAXED, __HIP_MEMORY_SCOPE_AGENT);
                __hip_atomic_store(ctrl + 1, g0 + 1u, __ATOMIC_RELEASE, __HIP_MEMORY_SCOPE_AGENT);
            } else {
                while (__hip_atomic_load(ctrl + 1, __ATOMIC_ACQUIRE, __HIP_MEMORY_SCOPE_AGENT) == g0)
                    __builtin_amdgcn_s_sleep(2);
            }
            __threadfence();
        }
        __syncthreads();

        // ---- y = Wy @ a_t + by ; write logits (B,T,V) ----
        {
            floatx4 yacc = {0.f, 0.f, 0.f, 0.f};
#pragma unroll
            for (int kk = 0; kk < 4; ++kk) {
                int kt = w * 4 + kk;
                bf16x8 a = *(const bf16x8*)(WyA + (size_t)(yi * 32 + kt) * 512 + l * 8);
                bf16x8 b = *(const bf16x8*)(aNxt + (size_t)(kt * 8 + yc) * 512 + l * 8);
                yacc = __builtin_amdgcn_mfma_f32_16x16x32_bf16(a, b, yacc, 0, 0, 0);
            }
            float* pw = pred + w * 256;
#pragma unroll
            for (int r = 0; r < 4; ++r) pw[(fq * 4 + r) * 16 + fm] = yacc[r];
        }
        __syncthreads();
        if (tid < 256) {
            int n = tid >> 4, m = tid & 15;    // consecutive lanes -> consecutive v: coalesced
            float s = 0.f;
#pragma unroll
            for (int ww = 0; ww < 8; ++ww) s += pred[ww * 256 + m * 16 + n];
            s += byp[ymrow + m];
            out[(size_t)(yc * 16 + n) * TV + (size_t)t * Vv + ymrow + m] = s;
        }
        __syncthreads();   // protect pred reuse next iteration
    }
}

// ---------- CE loss: one wave per row, 64 rows per wave ----------
__global__ __launch_bounds__(256) void loss_k(const float* __restrict__ logits, const int* __restrict__ Y,
                                              float* __restrict__ acc) {
    int w = threadIdx.x >> 6, l = threadIdx.x & 63;
    int rbase = blockIdx.x * 256 + w * 64;
    float sum = 0.f;
    for (int i = 0; i < 64; ++i) {
        const float* row = logits + (size_t)(rbase + i) * Vv;
        float4 v0 = *(const float4*)(row + l * 8);
        float4 v1 = *(const float4*)(row + l * 8 + 4);
        float vals[8] = {v0.x, v0.y, v0.z, v0.w, v1.x, v1.y, v1.z, v1.w};
        float mx = vals[0];
#pragma unroll
        for (int j = 1; j < 8; ++j) mx = fmaxf(mx, vals[j]);
#pragma unroll
        for (int s = 1; s < 64; s <<= 1) mx = fmaxf(mx, __shfl_xor(mx, s, 64));
        float es = 0.f;
#pragma unroll
        for (int j = 0; j < 8; ++j) es += __expf(vals[j] - mx);
#pragma unroll
        for (int s = 1; s < 64; s <<= 1) es += __shfl_xor(es, s, 64);
        int label = Y[rbase + i];
        float xl_local = vals[0];
#pragma unroll
        for (int j = 1; j < 8; ++j) xl_local = ((label & 7) == j) ? vals[j] : xl_local;
        float xl = __shfl(xl_local, label >> 3, 64);
        sum += (mx + __logf(es)) - xl;
    }
    if (l == 0) atomicAdd(acc, sum);
}

__global__ void finalize_k(const float* __restrict__ acc, float* __restrict__ out) {
    if (threadIdx.x == 0) out[(size_t)Bb * Tt * Vv] = acc[0] * (1.0f / (Bb * Tt));
}

extern "C" void kernel_launch(void* const* d_in, const int* in_sizes, int n_in,
                              void* d_out, int out_size, void* d_ws, size_t ws_size,
                              hipStream_t stream) {
    const float* X  = (const float*)d_in[0];
    const int*   Y  = (const int*)d_in[1];
    const float* Wf = (const float*)d_in[2];
    const float* bf = (const float*)d_in[3];
    const float* Wu = (const float*)d_in[4];
    const float* bu = (const float*)d_in[5];
    const float* Wc = (const float*)d_in[6];
    const float* bc = (const float*)d_in[7];
    const float* Wo = (const float*)d_in[8];
    const float* bo = (const float*)d_in[9];
    const float* Wy = (const float*)d_in[10];
    const float* by = (const float*)d_in[11];
    const float* ap = (const float*)d_in[12];
    const float* cp = (const float*)d_in[13];
    float* out = (float*)d_out;
    char* ws = (char*)d_ws;
    u16* WgA = (u16*)(ws + WS_WGA);
    u16* WyA = (u16*)(ws + WS_WYA);
    u16* aF0 = (u16*)(ws + WS_AF0);
    u16* aF1 = (u16*)(ws + WS_AF1);
    u32* ctrl = (u32*)(ws + WS_CTRL);
    float* lossAcc = (float*)(ws + WS_CTRL + 64);

    hipMemsetAsync((void*)ctrl, 0, 128, stream);
    pack_gates<<<3072, 256, 0, stream>>>(Wf, Wu, Wc, Wo, WgA);
    pack_wy<<<256, 256, 0, stream>>>(Wy, WyA);
    pack_a<<<512, 256, 0, stream>>>(ap, aF0);

    void* args[] = {(void*)&X, (void*)&bf, (void*)&bu, (void*)&bc, (void*)&bo, (void*)&by,
                    (void*)&cp, (void*)&WgA, (void*)&WyA, (void*)&aF0, (void*)&aF1,
                    (void*)&out, (void*)&ctrl};
    hipLaunchCooperativeKernel((void*)lstm_main, dim3(256), dim3(512), args, 0, stream);

    loss_k<<<256, 256, 0, stream>>>(out, Y, lossAcc);
    finalize_k<<<1, 64, 0, stream>>>(lossAcc, out);
}

// Round 2
// 14086.771 us; speedup vs baseline: 2.2479x; 2.2479x over previous
//
#include <hip/hip_runtime.h>

#define Hh 1024
#define Vv 512
#define Bb 128
#define Tt 512
#define TV (Tt * Vv) /* 262144 */

typedef unsigned short u16;
typedef unsigned int u32;
typedef __attribute__((ext_vector_type(8))) short bf16x8;
typedef __attribute__((ext_vector_type(4))) float floatx4;

// ---------- ws layout (bytes) ----------
#define WS_WGA 0                    // 4*64*48*512 u16 = 12,582,912 B
#define WS_WYA 12582912             // 32*32*512 u16   =  1,048,576 B
#define WS_AF0 13631488             // 131072 u16      =    262,144 B
#define WS_AF1 13893632             // 131072 u16      =    262,144 B
#define WS_CTRL 14155776            // flags u32[4][64] = 1024 B ; +1024: loss acc

__device__ __forceinline__ u16 f2bf(float f) {
    union { float f; u32 u; } c; c.f = f;
    u32 u = c.u + 0x7fffu + ((c.u >> 16) & 1u);   // RNE
    return (u16)(u >> 16);
}
__device__ __forceinline__ float sigm(float x) { return 1.0f / (1.0f + __expf(-x)); }
__device__ __forceinline__ float tanh_f(float x) {
    float e = __expf(-2.0f * fabsf(x));
    float t = (1.0f - e) / (1.0f + e);
    return x >= 0.0f ? t : -t;
}

// ---------- pack W{f,u,cc,o} (1024x1536 f32) -> fragment-linear bf16 ----------
__global__ __launch_bounds__(256) void pack_gates(const float* __restrict__ Wf, const float* __restrict__ Wu,
                                                  const float* __restrict__ Wc, const float* __restrict__ Wo,
                                                  u16* __restrict__ WgA) {
    int tid = blockIdx.x * 256 + threadIdx.x;  // 786432 total
    int l = tid & 63;
    int q = tid >> 6;
    int kt = q % 48; q /= 48;
    int i = q & 63;  int g = q >> 6;
    const float* W = (g == 0) ? Wf : (g == 1) ? Wu : (g == 2) ? Wc : Wo;
    int row = i * 16 + (l & 15);
    int k = kt * 32 + ((l >> 4) & 3) * 8;
    const float* src = W + (size_t)row * 1536 + k;
    float4 a = *(const float4*)src;
    float4 b = *(const float4*)(src + 4);
    bf16x8 v;
    v[0] = (short)f2bf(a.x); v[1] = (short)f2bf(a.y); v[2] = (short)f2bf(a.z); v[3] = (short)f2bf(a.w);
    v[4] = (short)f2bf(b.x); v[5] = (short)f2bf(b.y); v[6] = (short)f2bf(b.z); v[7] = (short)f2bf(b.w);
    *(bf16x8*)(WgA + (size_t)tid * 8) = v;
}

// ---------- pack Wy (512x1024 f32) -> fragment-linear bf16 ----------
__global__ __launch_bounds__(256) void pack_wy(const float* __restrict__ Wy, u16* __restrict__ WyA) {
    int tid = blockIdx.x * 256 + threadIdx.x;  // 65536 total
    int l = tid & 63;
    int q = tid >> 6;
    int kt = q & 31; int i = q >> 5;
    int row = i * 16 + (l & 15);
    int k = kt * 32 + ((l >> 4) & 3) * 8;
    const float* src = Wy + (size_t)row * 1024 + k;
    float4 a = *(const float4*)src;
    float4 b = *(const float4*)(src + 4);
    bf16x8 v;
    v[0] = (short)f2bf(a.x); v[1] = (short)f2bf(a.y); v[2] = (short)f2bf(a.z); v[3] = (short)f2bf(a.w);
    v[4] = (short)f2bf(b.x); v[5] = (short)f2bf(b.y); v[6] = (short)f2bf(b.z); v[7] = (short)f2bf(b.w);
    *(bf16x8*)(WyA + (size_t)tid * 8) = v;
}

// ---------- pack a_prev (H,B f32) -> fragment-linear bf16 a-buffer ----------
__global__ __launch_bounds__(256) void pack_a(const float* __restrict__ ap, u16* __restrict__ aF0) {
    int o = blockIdx.x * 256 + threadIdx.x;  // 131072 total
    int j = o & 7, li = (o >> 3) & 63, seg = o >> 9;
    int kt = seg >> 3, ch = seg & 7;
    int h = kt * 32 + ((li >> 4) & 3) * 8 + j;
    int b = ch * 16 + (li & 15);
    aF0[o] = f2bf(ap[(size_t)h * Bb + b]);
}

// ---------- main persistent LSTM kernel (cooperative, 256 blocks x 512 thr) ----------
// 4 independent column groups (32 cols each) of 64 blocks; group-local flag barrier.
__global__ __launch_bounds__(512, 2) void lstm_main(
    const float* __restrict__ X, const float* __restrict__ bfp, const float* __restrict__ bup,
    const float* __restrict__ bcp, const float* __restrict__ bop, const float* __restrict__ byp,
    const float* __restrict__ c_prev, const u16* __restrict__ WgA, const u16* __restrict__ WyA,
    u16* __restrict__ aF0, u16* __restrict__ aF1, float* __restrict__ out, u32* __restrict__ flags)
{
    __shared__ __align__(16) u16 xs[32768];     // 64 KB: x double-buffered, frag-linear
    __shared__ __align__(16) float predG[4096]; // 16 KB: gate partials
    __shared__ __align__(16) float predY[2048]; //  8 KB: y partials

    const int tid = threadIdx.x;
    const int bid = blockIdx.x;
    const int l = tid & 63;
    const int w = tid >> 6;        // wave 0..7
    const int g = w & 3;           // gate (f,u,cc,o)
    const int kh = w >> 2;         // K half (24 kt each)
    const int hc = bid & 63;       // h-chunk (16 rows); bid%8 = hc%8 -> weights XCD-local
    const int cc2 = bid >> 6;      // col chunk (32 cols) == group id
    const int c0 = cc2 * 32;
    const int fm = l & 15;
    const int fq = l >> 4;         // 0..3
    const int fk = fq * 8;
    u32* gFlags = flags + cc2 * 64;   // group-local 64 flags (256 B)

    // elementwise coords
    const int em = tid >> 5;       // 0..15
    const int en = tid & 31;       // 0..31
    const int hrow = hc * 16 + em;
    const int bcol = c0 + en;
    float c_val = c_prev[(size_t)hrow * Bb + bcol];
    const float bfv = bfp[hrow], buv = bup[hrow], bcv = bcp[hrow], bov = bop[hrow];
    const int a_kt = hrow >> 5;
    const int a_q = (hrow >> 3) & 3;
    const int a_j = hrow & 7;
    const int a_ch = bcol >> 4;
    const int a_lane = (a_q << 4) | (bcol & 15);
    const int aWidx = ((a_kt << 3) + a_ch) * 512 + a_lane * 8 + a_j;
    // y-GEMM tile
    const int yi = bid & 31;
    const int yc = bid >> 5;       // = cc2*2 + (hc>>5): stays inside group cols
    const int ymrow = yi * 16;

    const u16* Ab = WgA + (size_t)(g * 64 + hc) * 48 * 512;

    // ---- peel: stage x_0 into xs[0] ----
    {
        const float* Xt = X;
#pragma unroll
        for (int it = 0; it < 4; ++it) {
            int s = w + 8 * it;
            int kt2 = s >> 1, half = s & 1;
            int b = c0 + half * 16 + fm;
            const float* p = Xt + (size_t)b * TV + kt2 * 32 + fk;
            float4 x0 = *(const float4*)p;
            float4 x1 = *(const float4*)(p + 4);
            bf16x8 v;
            v[0] = (short)f2bf(x0.x); v[1] = (short)f2bf(x0.y); v[2] = (short)f2bf(x0.z); v[3] = (short)f2bf(x0.w);
            v[4] = (short)f2bf(x1.x); v[5] = (short)f2bf(x1.y); v[6] = (short)f2bf(x1.z); v[7] = (short)f2bf(x1.w);
            *(bf16x8*)(xs + s * 512 + l * 8) = v;
        }
    }
    __syncthreads();

    for (int t = 0; t < Tt; ++t) {
        const u16* aCur = (t & 1) ? aF1 : aF0;
        u16* aNxt = (t & 1) ? aF0 : aF1;
        const u16* xcur = xs + (t & 1) * 16384;

        // ---- 1. gate GEMM: wave (g, kh): 16x32 partial over 24 k-tiles ----
        floatx4 acc0 = {0.f, 0.f, 0.f, 0.f}, acc1 = {0.f, 0.f, 0.f, 0.f};
        {
            const int kt0 = kh * 24;
#pragma unroll
            for (int kk = 0; kk < 24; ++kk) {
                int kt = kt0 + kk;
                bf16x8 a = *(const bf16x8*)(Ab + (size_t)kt * 512 + l * 8);
                bf16x8 b0, b1;
                if (kt < 32) {
                    int seg = kt * 8 + cc2 * 2;
                    b0 = *(const bf16x8*)(aCur + (size_t)seg * 512 + l * 8);
                    b1 = *(const bf16x8*)(aCur + (size_t)(seg + 1) * 512 + l * 8);
                } else {
                    int s = (kt - 32) * 2;
                    b0 = *(const bf16x8*)(xcur + s * 512 + l * 8);
                    b1 = *(const bf16x8*)(xcur + (s + 1) * 512 + l * 8);
                }
                acc0 = __builtin_amdgcn_mfma_f32_16x16x32_bf16(a, b0, acc0, 0, 0, 0);
                acc1 = __builtin_amdgcn_mfma_f32_16x16x32_bf16(a, b1, acc1, 0, 0, 0);
            }
        }
        {
            float* pw = predG + w * 512;
#pragma unroll
            for (int r = 0; r < 4; ++r) {
                int m = fq * 4 + r;
                pw[m * 32 + fm] = acc0[r];
                pw[m * 32 + 16 + fm] = acc1[r];
            }
        }
        __syncthreads();  // 2.

        // ---- 3. elementwise gates, c/a update ----
        {
            int o = em * 32 + en;
            float gf = predG[o]            + predG[4 * 512 + o] + bfv;
            float gu = predG[512 + o]      + predG[5 * 512 + o] + buv;
            float gc = predG[2 * 512 + o]  + predG[6 * 512 + o] + bcv;
            float go = predG[3 * 512 + o]  + predG[7 * 512 + o] + bov;
            float f = sigm(gf), u = sigm(gu), cc = tanh_f(gc), oo = sigm(go);
            c_val = f * c_val + u * cc;
            float a_new = oo * tanh_f(c_val);
            aNxt[aWidx] = f2bf(a_new);
        }
        __syncthreads();  // 4. all aNxt stores issued & waited

        // ---- 5. barrier arrival: one release-flag per block ----
        if (tid == 0) {
            __threadfence();
            __hip_atomic_store(gFlags + hc, (u32)(t + 1), __ATOMIC_RELEASE, __HIP_MEMORY_SCOPE_AGENT);
        }

        // ---- 6. prefetch x_{t+1} into other LDS buffer (hides in barrier window) ----
        if (t + 1 < Tt) {
            const float* Xt = X + (size_t)(t + 1) * Vv;
            u16* xnxt = xs + ((t + 1) & 1) * 16384;
#pragma unroll
            for (int it = 0; it < 4; ++it) {
                int s = w + 8 * it;
                int kt2 = s >> 1, half = s & 1;
                int b = c0 + half * 16 + fm;
                const float* p = Xt + (size_t)b * TV + kt2 * 32 + fk;
                float4 x0 = *(const float4*)p;
                float4 x1 = *(const float4*)(p + 4);
                bf16x8 v;
                v[0] = (short)f2bf(x0.x); v[1] = (short)f2bf(x0.y); v[2] = (short)f2bf(x0.z); v[3] = (short)f2bf(x0.w);
                v[4] = (short)f2bf(x1.x); v[5] = (short)f2bf(x1.y); v[6] = (short)f2bf(x1.z); v[7] = (short)f2bf(x1.w);
                *(bf16x8*)(xnxt + s * 512 + l * 8) = v;
            }
        }

        // ---- 7. barrier wait: wave 0, lane i polls block i's flag ----
        if (tid < 64) {
            u32 gen = (u32)(t + 1);
            while (1) {
                u32 v = __hip_atomic_load(gFlags + l, __ATOMIC_RELAXED, __HIP_MEMORY_SCOPE_AGENT);
                if (__all(v >= gen)) break;
            }
            __threadfence();   // acquire: invalidate stale L1/L2 lines
        }
        __syncthreads();  // 8.

        // ---- 9. y = Wy @ a_t + by ; write logits (B,T,V) ----
        {
            floatx4 yacc = {0.f, 0.f, 0.f, 0.f};
#pragma unroll
            for (int kk = 0; kk < 4; ++kk) {
                int kt = w * 4 + kk;
                bf16x8 a = *(const bf16x8*)(WyA + (size_t)(yi * 32 + kt) * 512 + l * 8);
                bf16x8 b = *(const bf16x8*)(aNxt + (size_t)(kt * 8 + yc) * 512 + l * 8);
                yacc = __builtin_amdgcn_mfma_f32_16x16x32_bf16(a, b, yacc, 0, 0, 0);
            }
            float* pw = predY + w * 256;
#pragma unroll
            for (int r = 0; r < 4; ++r) pw[(fq * 4 + r) * 16 + fm] = yacc[r];
        }
        __syncthreads();
        if (tid < 256) {
            int n = tid >> 4, m = tid & 15;
            float s = 0.f;
#pragma unroll
            for (int ww = 0; ww < 8; ++ww) s += predY[ww * 256 + m * 16 + n];
            s += byp[ymrow + m];
            out[(size_t)(yc * 16 + n) * TV + (size_t)t * Vv + ymrow + m] = s;
        }
        // no extra sync needed: predY rewrite at t+1 is separated by syncs 2/4/8
    }
}

// ---------- CE loss ----------
__global__ __launch_bounds__(256) void loss_k(const float* __restrict__ logits, const int* __restrict__ Y,
                                              float* __restrict__ acc) {
    int w = threadIdx.x >> 6, l = threadIdx.x & 63;
    int rbase = blockIdx.x * 256 + w * 64;
    float sum = 0.f;
    for (int i = 0; i < 64; ++i) {
        const float* row = logits + (size_t)(rbase + i) * Vv;
        float4 v0 = *(const float4*)(row + l * 8);
        float4 v1 = *(const float4*)(row + l * 8 + 4);
        float vals[8] = {v0.x, v0.y, v0.z, v0.w, v1.x, v1.y, v1.z, v1.w};
        float mx = vals[0];
#pragma unroll
        for (int j = 1; j < 8; ++j) mx = fmaxf(mx, vals[j]);
#pragma unroll
        for (int s = 1; s < 64; s <<= 1) mx = fmaxf(mx, __shfl_xor(mx, s, 64));
        float es = 0.f;
#pragma unroll
        for (int j = 0; j < 8; ++j) es += __expf(vals[j] - mx);
#pragma unroll
        for (int s = 1; s < 64; s <<= 1) es += __shfl_xor(es, s, 64);
        int label = Y[rbase + i];
        float xl_local = vals[0];
#pragma unroll
        for (int j = 1; j < 8; ++j) xl_local = ((label & 7) == j) ? vals[j] : xl_local;
        float xl = __shfl(xl_local, label >> 3, 64);
        sum += (mx + __logf(es)) - xl;
    }
    if (l == 0) atomicAdd(acc, sum);
}

__global__ void finalize_k(const float* __restrict__ acc, float* __restrict__ out) {
    if (threadIdx.x == 0) out[(size_t)Bb * Tt * Vv] = acc[0] * (1.0f / (Bb * Tt));
}

extern "C" void kernel_launch(void* const* d_in, const int* in_sizes, int n_in,
                              void* d_out, int out_size, void* d_ws, size_t ws_size,
                              hipStream_t stream) {
    const float* X  = (const float*)d_in[0];
    const int*   Y  = (const int*)d_in[1];
    const float* Wf = (const float*)d_in[2];
    const float* bf = (const float*)d_in[3];
    const float* Wu = (const float*)d_in[4];
    const float* bu = (const float*)d_in[5];
    const float* Wc = (const float*)d_in[6];
    const float* bc = (const float*)d_in[7];
    const float* Wo = (const float*)d_in[8];
    const float* bo = (const float*)d_in[9];
    const float* Wy = (const float*)d_in[10];
    const float* by = (const float*)d_in[11];
    const float* ap = (const float*)d_in[12];
    const float* cp = (const float*)d_in[13];
    float* out = (float*)d_out;
    char* ws = (char*)d_ws;
    u16* WgA = (u16*)(ws + WS_WGA);
    u16* WyA = (u16*)(ws + WS_WYA);
    u16* aF0 = (u16*)(ws + WS_AF0);
    u16* aF1 = (u16*)(ws + WS_AF1);
    u32* flags = (u32*)(ws + WS_CTRL);
    float* lossAcc = (float*)(ws + WS_CTRL + 1024);

    hipMemsetAsync((void*)flags, 0, 2048, stream);
    pack_gates<<<3072, 256, 0, stream>>>(Wf, Wu, Wc, Wo, WgA);
    pack_wy<<<256, 256, 0, stream>>>(Wy, WyA);
    pack_a<<<512, 256, 0, stream>>>(ap, aF0);

    void* args[] = {(void*)&X, (void*)&bf, (void*)&bu, (void*)&bc, (void*)&bo, (void*)&by,
                    (void*)&cp, (void*)&WgA, (void*)&WyA, (void*)&aF0, (void*)&aF1,
                    (void*)&out, (void*)&flags};
    hipLaunchCooperativeKernel((void*)lstm_main, dim3(256), dim3(512), args, 0, stream);

    loss_k<<<256, 256, 0, stream>>>(out, Y, lossAcc);
    finalize_k<<<1, 64, 0, stream>>>(lossAcc, out);
}